// Round 1
// baseline (1486.059 us; speedup 1.0000x reference)
//
#include <hip/hip_runtime.h>
#include <cstddef>

typedef short short8 __attribute__((ext_vector_type(8)));
typedef float f32x4 __attribute__((ext_vector_type(4)));
typedef unsigned short u16;

// problem dims
#define Bn 512
#define Tn 64
#define En 1024
#define An 32
#define Sn 30
#define Dn 200
#define Hn 200
#define SSn 230
#define OUTC 380

// packed weight regions, element (u16) offsets inside d_ws
// Winp: Kp320(KT10) x Np208(NT13) ; Wgru: 416(13) x 608(38) ; Wimg/Wobsd: 224(7) x 208(13)
// Wims/Wobss: 224(7) x 64(4) ; Wobse: 1024(32) x 208(13)
#define U16_WINP  0
#define EL_WINP   66560
#define U16_WGRU  66560
#define EL_WGRU   252928
#define U16_WIMG  319488
#define EL_WIMG   46592
#define U16_WOBSD 366080
#define EL_WOBSD  46592
#define U16_WIMS  412672
#define EL_WIMS   14336
#define U16_WOBSS 427008
#define EL_WOBSS  14336
#define U16_WOBSE 441344
#define EL_WOBSE  212992
#define U16_TOTAL 654336
#define PREOBS_BYTE_OFF 1308672   // 654336*2, 16B aligned

#define DEV static __device__ __forceinline__

DEV u16 f2bf(float f) {
  union { float f; unsigned u; } v; v.f = f;
  return (u16)((v.u + 0x7FFFu + ((v.u >> 16) & 1u)) >> 16);
}
DEV float bf2f(u16 h) {
  union { unsigned u; float f; } v; v.u = ((unsigned)h) << 16; return v.f;
}
DEV float elu1(float x)  { return x > 0.f ? x : expm1f(x); }
DEV float sigm(float x)  { return 1.f / (1.f + expf(-x)); }
DEV float splus(float x) { return x > 20.f ? x : log1pf(expf(x)); }

// ---------------------------------------------------------------- pack kernel
// B-fragment order for mfma_f32_16x16x32_bf16:
//   dst[((nt*KT+kt)*64 + lane)*8 + j] = W[kt*32 + (lane>>4)*8 + j][nt*16 + (lane&15)]
DEV void pack_one(const float* src, u16* dst, int li, int KT,
                  int Kr, int Nr, int ldN, int roff) {
  int j = li & 7, lane = (li >> 3) & 63, frag = li >> 9;
  int kt = frag % KT, nt = frag / KT;
  int k = kt * 32 + ((lane >> 4) << 3) + j;
  int n = nt * 16 + (lane & 15);
  float v = (k < Kr && n < Nr) ? src[(size_t)(k + roff) * ldN + n] : 0.f;
  dst[li] = f2bf(v);
}

__global__ __launch_bounds__(256) void k_pack(
    const float* w_inp, const float* w_gru, const float* w_img,
    const float* w_obs, const float* w_ims, const float* w_obss,
    u16* ws) {
  int idx = blockIdx.x * 256 + threadIdx.x;
  if (idx < U16_WGRU)       pack_one(w_inp,  ws + U16_WINP,  idx - U16_WINP, 10, 292, 200, 200, 0);
  else if (idx < U16_WIMG)  pack_one(w_gru,  ws + U16_WGRU,  idx - U16_WGRU, 13, 400, 600, 600, 0);
  else if (idx < U16_WOBSD) pack_one(w_img,  ws + U16_WIMG,  idx - U16_WIMG,  7, 200, 200, 200, 0);
  else if (idx < U16_WIMS)  pack_one(w_obs,  ws + U16_WOBSD, idx - U16_WOBSD, 7, 200, 200, 200, 0);
  else if (idx < U16_WOBSS) pack_one(w_ims,  ws + U16_WIMS,  idx - U16_WIMS,  7, 200,  60,  60, 0);
  else if (idx < U16_WOBSE) pack_one(w_obss, ws + U16_WOBSS, idx - U16_WOBSS, 7, 200,  60,  60, 0);
  else if (idx < U16_TOTAL) pack_one(w_obs,  ws + U16_WOBSE, idx - U16_WOBSE, 32, 1024, 200, 200, 200);
}

// ------------------------------------------------------------- preobs kernel
// preobs[t*512+b][n<200] = emb[b][t][:] @ w_obs_out[200:1224][:]
__global__ __launch_bounds__(256) void k_preobs(
    const float* __restrict__ emb, const u16* __restrict__ ws,
    float* __restrict__ pre) {
  __shared__ u16 Asm[64 * 72];          // [64 rows][64 k + 8 pad]
  __shared__ short8 Bsm[26 * 64];       // 2 kt x 13 nt fragments
  const short8* Wp = (const short8*)(ws + U16_WOBSE);

  int tid = threadIdx.x, wv = tid >> 6, lane = tid & 63;
  int lrow = lane & 15, quad = lane >> 4;
  int m0 = blockIdx.x * 64;
  int t = m0 >> 9, brow0 = m0 & 511;

  f32x4 acc[13];
  const f32x4 z4 = {0.f, 0.f, 0.f, 0.f};
#pragma unroll
  for (int i = 0; i < 13; ++i) acc[i] = z4;

  for (int kc = 0; kc < 16; ++kc) {     // K chunks of 64
    __syncthreads();
    // stage A: 64 rows x 64 els (fp32 -> bf16)
#pragma unroll
    for (int q = 0; q < 4; ++q) {
      int i = tid + q * 256;            // 0..1023 float4s
      int row = i >> 4, c4 = i & 15;
      const float* src = emb + ((size_t)((brow0 + row) * Tn + t)) * En + kc * 64 + c4 * 4;
      float4 v = *(const float4*)src;
      union { u16 h[4]; unsigned long long ll; } p;
      p.h[0] = f2bf(v.x); p.h[1] = f2bf(v.y); p.h[2] = f2bf(v.z); p.h[3] = f2bf(v.w);
      *(unsigned long long*)&Asm[row * 72 + c4 * 4] = p.ll;
    }
    // stage B: copy 26 fragments (1664 short8)
    for (int q = 0; q < 7; ++q) {
      int i = tid + q * 256;
      if (i < 1664) {
        int pair = i >> 6, l = i & 63;
        int ktl = pair / 13, nt = pair % 13;
        Bsm[i] = Wp[(nt * 32 + kc * 2 + ktl) * 64 + l];
      }
    }
    __syncthreads();
#pragma unroll
    for (int ktl = 0; ktl < 2; ++ktl) {
      short8 a = *(const short8*)&Asm[(wv * 16 + lrow) * 72 + ktl * 32 + quad * 8];
#pragma unroll
      for (int nt = 0; nt < 13; ++nt)
        acc[nt] = __builtin_amdgcn_mfma_f32_16x16x32_bf16(a, Bsm[(ktl * 13 + nt) * 64 + lane], acc[nt], 0, 0, 0);
    }
  }
  // epilogue
#pragma unroll
  for (int nt = 0; nt < 13; ++nt) {
    int col = nt * 16 + lrow;
    if (col < 200) {
#pragma unroll
      for (int r = 0; r < 4; ++r) {
        int m = m0 + wv * 16 + quad * 4 + r;
        pre[(size_t)m * 200 + col] = acc[nt][r];
      }
    }
  }
}

// ---------------------------------------------------------------- scan kernel
// 32 blocks x 512 threads; block owns batch rows b0..b0+15 for all 64 steps.
__global__ __launch_bounds__(512, 2) void k_scan(
    const float* __restrict__ g_ctx, const float* __restrict__ g_act,
    const float* __restrict__ g_np, const float* __restrict__ g_no,
    const float* __restrict__ b_inp, const float* __restrict__ b_gru,
    const float* __restrict__ b_img, const float* __restrict__ b_obs,
    const float* __restrict__ b_ims, const float* __restrict__ b_obss,
    const u16* __restrict__ ws, const float* __restrict__ pre,
    float* __restrict__ out) {

  // LDS regions (56,576 B total)
  __shared__ u16 gin[16 * 424];   // k 0..199 x, 200..399 deter, 400..423 pad0
  __shared__ u16 U[16 * 616];     // union: inp [16][328] / parts [16][616]
  __shared__ u16 hA[16 * 232];    // h (prior branch), k pad 200..231 = 0
  __shared__ u16 hoA[16 * 232];   // ho (posterior branch)
  __shared__ float stp[16 * 66];
  __shared__ float sto[16 * 66];

  const short8* Winp  = (const short8*)(ws + U16_WINP);
  const short8* Wgru  = (const short8*)(ws + U16_WGRU);
  const short8* Wimg  = (const short8*)(ws + U16_WIMG);
  const short8* Wobsd = (const short8*)(ws + U16_WOBSD);
  const short8* Wims  = (const short8*)(ws + U16_WIMS);
  const short8* Wobss = (const short8*)(ws + U16_WOBSS);

  int tid = threadIdx.x, wv = tid >> 6, lane = tid & 63;
  int lrow = lane & 15, quad = lane >> 4;
  int b0 = blockIdx.x * 16;
  const f32x4 z4 = {0.f, 0.f, 0.f, 0.f};

  // zero-init carry + pads
  for (int i = tid; i < 16 * 424; i += 512) gin[i] = 0;
  for (int i = tid; i < 16 * 616; i += 512) U[i] = 0;
  for (int i = tid; i < 16 * 232; i += 512) { hA[i] = 0; hoA[i] = 0; }
  __syncthreads();

  for (int t = 0; t < Tn; ++t) {
    // ---- load ctx/act for this step into U.inp (stride 328), re-zero pads
    {
      int row = tid >> 5, sub = tid & 31;
      const float* crow = g_ctx + ((size_t)(b0 + row) * Tn + t) * SSn;
      for (int i = sub; i < SSn; i += 32) U[row * 328 + 30 + i] = f2bf(crow[i]);
      const float* arow = g_act + ((size_t)(b0 + row) * Tn + t) * An;
      if (sub < An) U[row * 328 + 260 + sub] = f2bf(arow[sub]);
      if (sub < 28) U[row * 328 + 292 + sub] = 0;   // parts overlay clobbers pads
    }
    __syncthreads();

    // ---- stage A: x = elu([stoch,ctx,act] @ w_inp + b)  -> gin[:,0:200]
    for (int nt = wv; nt < 13; nt += 8) {
      f32x4 acc = z4;
      const short8* bp = Winp + (size_t)(nt * 10) * 64 + lane;
#pragma unroll
      for (int kt = 0; kt < 10; ++kt) {
        short8 a = *(const short8*)&U[lrow * 328 + kt * 32 + quad * 8];
        acc = __builtin_amdgcn_mfma_f32_16x16x32_bf16(a, bp[kt * 64], acc, 0, 0, 0);
      }
      int col = nt * 16 + lrow;
      if (col < 200) {
        float bias = b_inp[col];
#pragma unroll
        for (int r = 0; r < 4; ++r)
          gin[(quad * 4 + r) * 424 + col] = f2bf(elu1(acc[r] + bias));
      }
    }
    __syncthreads();

    // ---- stage B: parts = [x, deter] @ w_gru + b  -> U.parts (bf16)
    for (int nt = wv; nt < 38; nt += 8) {
      f32x4 acc = z4;
      const short8* bp = Wgru + (size_t)(nt * 13) * 64 + lane;
#pragma unroll
      for (int kt = 0; kt < 13; ++kt) {
        short8 a = *(const short8*)&gin[lrow * 424 + kt * 32 + quad * 8];
        acc = __builtin_amdgcn_mfma_f32_16x16x32_bf16(a, bp[kt * 64], acc, 0, 0, 0);
      }
      int col = nt * 16 + lrow;
      if (col < 600) {
        float bias = b_gru[col];
#pragma unroll
        for (int r = 0; r < 4; ++r)
          U[(quad * 4 + r) * 616 + col] = f2bf(acc[r] + bias);
      }
    }
    __syncthreads();

    // ---- GRU elementwise: deter_new -> gin deter slot + out
    for (int i = tid; i < 16 * Dn; i += 512) {
      int row = i / Dn, d = i % Dn;
      float rg = bf2f(U[row * 616 + d]);
      float cg = bf2f(U[row * 616 + 200 + d]);
      float ug = bf2f(U[row * 616 + 400 + d]);
      float dold = bf2f(gin[row * 424 + 200 + d]);
      float rs  = sigm(rg);
      float cnd = tanhf(rs * cg);
      float up  = sigm(ug - 1.f);
      float dn  = up * cnd + (1.f - up) * dold;
      gin[row * 424 + 200 + d] = f2bf(dn);
      __builtin_nontemporal_store(dn, &out[((size_t)(b0 + row) * Tn + t) * OUTC + 180 + d]);
    }
    __syncthreads();

    // ---- stage C: h = elu(deter@Wimg+b), ho = elu(deter@Wobsd + preobs + b)
    for (int j = wv; j < 26; j += 8) {
      bool isobs = j >= 13;
      int nt = isobs ? j - 13 : j;
      const short8* bp = (isobs ? Wobsd : Wimg) + (size_t)(nt * 7) * 64 + lane;
      f32x4 acc = z4;
#pragma unroll
      for (int kt = 0; kt < 7; ++kt) {
        short8 a = *(const short8*)&gin[lrow * 424 + 200 + kt * 32 + quad * 8];
        acc = __builtin_amdgcn_mfma_f32_16x16x32_bf16(a, bp[kt * 64], acc, 0, 0, 0);
      }
      int col = nt * 16 + lrow;
      if (col < 200) {
        if (!isobs) {
          float bias = b_img[col];
#pragma unroll
          for (int r = 0; r < 4; ++r)
            hA[(quad * 4 + r) * 232 + col] = f2bf(elu1(acc[r] + bias));
        } else {
          float bias = b_obs[col];
#pragma unroll
          for (int r = 0; r < 4; ++r) {
            int row = quad * 4 + r;
            float po = pre[((size_t)t * Bn + b0 + row) * 200 + col];
            hoA[row * 232 + col] = f2bf(elu1(acc[r] + bias + po));
          }
        }
      }
    }
    __syncthreads();

    // ---- stage D: st = h@Wims+b, so = ho@Wobss+b  (8 tiles, 1 per wave)
    {
      bool isobs = wv >= 4;
      int nt = wv & 3;
      const short8* bp = (isobs ? Wobss : Wims) + (size_t)(nt * 7) * 64 + lane;
      const u16* src = isobs ? hoA : hA;
      f32x4 acc = z4;
#pragma unroll
      for (int kt = 0; kt < 7; ++kt) {
        short8 a = *(const short8*)&src[lrow * 232 + kt * 32 + quad * 8];
        acc = __builtin_amdgcn_mfma_f32_16x16x32_bf16(a, bp[kt * 64], acc, 0, 0, 0);
      }
      int col = nt * 16 + lrow;
      if (col < 60) {
        float bias = (isobs ? b_obss : b_ims)[col];
        float* dst = isobs ? sto : stp;
#pragma unroll
        for (int r = 0; r < 4; ++r)
          dst[(quad * 4 + r) * 66 + col] = acc[r] + bias;
      }
    }
    __syncthreads();

    // ---- final epilogue: stats, noises, outputs, next stoch
    if (tid < 480) {
      int row = tid / 30, s = tid % 30;
      size_t ob = ((size_t)(b0 + row) * Tn + t) * OUTC;
      size_t ni = ((size_t)t * Bn + b0 + row) * Sn + s;
      float pm = stp[row * 66 + s];
      float ps = splus(stp[row * 66 + 30 + s]) + 0.1f;
      float pst = pm + ps * g_np[ni];
      float om = sto[row * 66 + s];
      float os = splus(sto[row * 66 + 30 + s]) + 0.1f;
      float ost = om + os * g_no[ni];
      __builtin_nontemporal_store(om,  &out[ob + s]);
      __builtin_nontemporal_store(os,  &out[ob + 30 + s]);
      __builtin_nontemporal_store(ost, &out[ob + 60 + s]);
      __builtin_nontemporal_store(pm,  &out[ob + 90 + s]);
      __builtin_nontemporal_store(ps,  &out[ob + 120 + s]);
      __builtin_nontemporal_store(pst, &out[ob + 150 + s]);
      U[row * 328 + s] = f2bf(ost);     // stoch carry for next step
    }
    __syncthreads();
  }
}

extern "C" void kernel_launch(void* const* d_in, const int* in_sizes, int n_in,
                              void* d_out, int out_size, void* d_ws, size_t ws_size,
                              hipStream_t stream) {
  (void)in_sizes; (void)n_in; (void)out_size; (void)ws_size;
  const float* emb    = (const float*)d_in[0];
  const float* action = (const float*)d_in[1];
  const float* ctx    = (const float*)d_in[2];
  const float* np_    = (const float*)d_in[3];
  const float* no_    = (const float*)d_in[4];
  const float* w_inp  = (const float*)d_in[5];
  const float* b_inp  = (const float*)d_in[6];
  const float* w_gru  = (const float*)d_in[7];
  const float* b_gru  = (const float*)d_in[8];
  const float* w_img  = (const float*)d_in[9];
  const float* b_img  = (const float*)d_in[10];
  const float* w_obs  = (const float*)d_in[11];
  const float* b_obs  = (const float*)d_in[12];
  const float* w_ims  = (const float*)d_in[13];
  const float* b_ims  = (const float*)d_in[14];
  const float* w_obss = (const float*)d_in[15];
  const float* b_obss = (const float*)d_in[16];

  u16*   wsu = (u16*)d_ws;
  float* pre = (float*)((char*)d_ws + PREOBS_BYTE_OFF);
  float* out = (float*)d_out;

  k_pack<<<2556, 256, 0, stream>>>(w_inp, w_gru, w_img, w_obs, w_ims, w_obss, wsu);
  k_preobs<<<512, 256, 0, stream>>>(emb, wsu, pre);
  k_scan<<<32, 512, 0, stream>>>(ctx, action, np_, no_,
                                 b_inp, b_gru, b_img, b_obs, b_ims, b_obss,
                                 wsu, pre, out);
}